// Round 5
// baseline (9631.014 us; speedup 1.0000x reference)
//
#include <hip/hip_runtime.h>

// DKVMN fused forward, round 5.
// grid = B = 256 blocks x 512 threads (8 waves = 2/SIMD -> VGPR cap 256).
// R4 diagnosis: compiler kept VGPR=64 and re-read e/a from LDS every chunk
// (16x ds_read_b128 + 16x ds_read_b32 per 2-row iter) -> CU-shared LDS pipe
// ~30us/pass. Fix: (a) 2 waves/SIMD for a 256-reg budget; (b) load e/a into
// registers once per pass and PIN them with empty asm ("+v") so the allocator
// cannot rematerialize from LDS; (c) w read as broadcast float2; (d) gates
// tiled 2d x 8u with redundant weight loads made same-address (ug = low bits).
// State: fp16 in d_ws (64 MB, L3-resident), U=8 steps/pass, 64 passes.
// LDS: wv 32K + e 32K + a 32K + q 2K + r 8K + h1 2K = 108 KB, 1 block/CU.

#define B_ 256
#define T_ 512
#define N_ 512
#define DK_ 64
#define DV_ 256
#define S_ 64
#define U_ 8
#define SU_ 32
#define NTB 512
#define NSUPER (T_ / SU_)   // 16
#define PPS (SU_ / U_)      // 4

typedef _Float16 h16;
typedef __attribute__((ext_vector_type(4))) _Float16 half4;

__device__ __forceinline__ float dot4(float4 a, float4 b) {
  return a.x * b.x + a.y * b.y + a.z * b.z + a.w * b.w;
}
__device__ __forceinline__ float4 h2f(half4 h) {
  return make_float4((float)h.x, (float)h.y, (float)h.z, (float)h.w);
}
__device__ __forceinline__ half4 f2h(float4 f) {
  half4 h;
  h.x = (h16)f.x; h.y = (h16)f.y; h.z = (h16)f.z; h.w = (h16)f.w;
  return h;
}
// Pin a float4 pair into VGPRs: asm "defines" the values, so the compiler
// cannot re-materialize them from their LDS source inside the loop.
#define PIN8(e, a)                                                        \
  asm volatile("" : "+v"(e.x), "+v"(e.y), "+v"(e.z), "+v"(e.w),           \
                    "+v"(a.x), "+v"(a.y), "+v"(a.z), "+v"(a.w))

__global__ void __attribute__((amdgpu_flat_work_group_size(NTB, NTB),
                               amdgpu_waves_per_eu(2)))
dkvmn_fused(
    const int* __restrict__ concepts, const int* __restrict__ interactions,
    const float* __restrict__ Kmem, const float* __restrict__ Vmem,
    const float* __restrict__ cemb, const float* __restrict__ iemb,
    const float* __restrict__ We, const float* __restrict__ be,
    const float* __restrict__ Wa, const float* __restrict__ ba,
    const float* __restrict__ W1, const float* __restrict__ b1,
    const float* __restrict__ W2, const float* __restrict__ b2,
    const float* __restrict__ W3, const float* __restrict__ b3,
    float* __restrict__ out, h16* __restrict__ state) {
  __shared__ float s_wv[SU_ * DV_];  // 32 KB: v[32][256] gate phase; w[8][512] passes
  __shared__ float s_e[SU_][DV_];    // 32 KB
  __shared__ float s_a[SU_][DV_];    // 32 KB
  __shared__ float s_q[U_][DK_];     // 2 KB
  __shared__ float s_r[U_][DV_];     // 8 KB
  __shared__ float s_h1[U_][S_];     // 2 KB
  float (*s_w)[N_] = (float(*)[N_])s_wv;

  const int tid = threadIdx.x;
  const int b = blockIdx.x;
  const int lane = tid & 63;
  const int wid = tid >> 6;  // 8 waves
  half4* stb = (half4*)state + (size_t)b * (N_ * DV_ / 4);

  // ---- init fp16 state from Vmem ----
  {
    const float4* vm4 = (const float4*)Vmem;
    for (int idx = tid; idx < N_ * DV_ / 4; idx += NTB) stb[idx] = f2h(vm4[idx]);
  }

  for (int sp = 0; sp < NSUPER; ++sp) {
    const int s0 = sp * SU_;
    __syncthreads();  // G0: prev super-pass readers of s_wv/s_e/s_a done

    // ---- stage v: 32 steps of interaction embeds ----
    {
      const float4* iemb4 = (const float4*)iemb;
      for (int idx = tid; idx < SU_ * (DV_ / 4); idx += NTB) {
        const int u32 = idx >> 6, f = idx & 63;
        const int iv = interactions[b * T_ + s0 + u32];
        *(float4*)&s_wv[u32 * DV_ + f * 4] =
            iv ? iemb4[(size_t)iv * (DV_ / 4) + f] : make_float4(0.f, 0.f, 0.f, 0.f);
      }
    }
    __syncthreads();  // G1: v staged

    // ---- gates for 32 steps: thread owns 2 d's x 8 u's ----
    // ug = tid&3 (low bits): lanes 0..3 share dp -> weight loads are
    // same-address within the wave (L1 broadcast); v-reads 4-way broadcast.
    {
      const int ug = tid & 3, dp = tid >> 2;
      const int d0 = 2 * dp, d1 = 2 * dp + 1;
      float accE0[8], accE1[8], accA0[8], accA1[8];
#pragma unroll
      for (int j = 0; j < 8; ++j) { accE0[j] = accE1[j] = accA0[j] = accA1[j] = 0.f; }
      const float4* We4 = (const float4*)We;
      const float4* Wa4 = (const float4*)Wa;
      for (int kk = 0; kk < DV_ / 4; ++kk) {
        const float4 we0 = We4[(size_t)d0 * 64 + kk], we1 = We4[(size_t)d1 * 64 + kk];
        const float4 wa0 = Wa4[(size_t)d0 * 64 + kk], wa1 = Wa4[(size_t)d1 * 64 + kk];
#pragma unroll
        for (int j = 0; j < 8; ++j) {
          const float4 v4 = *(const float4*)&s_wv[(ug * 8 + j) * DV_ + kk * 4];
          accE0[j] += dot4(we0, v4);
          accE1[j] += dot4(we1, v4);
          accA0[j] += dot4(wa0, v4);
          accA1[j] += dot4(wa1, v4);
        }
      }
      const float be0 = be[d0], be1 = be[d1], ba0 = ba[d0], ba1 = ba[d1];
#pragma unroll
      for (int j = 0; j < 8; ++j) {
        const int u = ug * 8 + j;
        s_e[u][d0] = 1.f / (1.f + expf(-(accE0[j] + be0)));
        s_e[u][d1] = 1.f / (1.f + expf(-(accE1[j] + be1)));
        s_a[u][d0] = tanhf(accA0[j] + ba0);
        s_a[u][d1] = tanhf(accA1[j] + ba1);
      }
    }
    // gate writes ordered before stream reads by barriers A..D of pass 0.

    for (int p = 0; p < PPS; ++p) {
      const int t0 = s0 + p * U_;
      const int ub = p * U_;
      __syncthreads();  // A: prev MLP done with s_q/s_r/s_h1; gates done (p==0)

      // ---- stage q: 512 threads = 8u x 64 ----
      {
        const int c = concepts[b * T_ + t0 + wid];
        s_q[wid][lane] = c ? cemb[c * DK_ + lane] : 0.f;
      }
      __syncthreads();  // B

      // ---- logits: n = tid, 8 u's per thread ----
      {
        const int n = tid;
        const float4* kr = (const float4*)(Kmem + n * DK_);
        float acc[8];
#pragma unroll
        for (int j = 0; j < 8; ++j) acc[j] = 0.f;
#pragma unroll
        for (int kk = 0; kk < DK_ / 4; ++kk) {
          const float4 k4 = kr[kk];
#pragma unroll
          for (int j = 0; j < 8; ++j)
            acc[j] += dot4(k4, *(const float4*)&s_q[j][kk * 4]);
        }
#pragma unroll
        for (int j = 0; j < 8; ++j) s_w[j][n] = acc[j];
      }
      __syncthreads();  // C

      // ---- softmax (wave wid owns u=wid) + zero s_r ----
      {
        const int u = wid;
        *(float4*)&s_r[u][lane * 4] = make_float4(0.f, 0.f, 0.f, 0.f);
        float lg[8], mx = -1e30f;
#pragma unroll
        for (int k = 0; k < 8; ++k) {
          lg[k] = s_w[u][lane + 64 * k];
          mx = fmaxf(mx, lg[k]);
        }
        for (int off = 32; off > 0; off >>= 1) mx = fmaxf(mx, __shfl_xor(mx, off, 64));
        float sum = 0.f;
#pragma unroll
        for (int k = 0; k < 8; ++k) {
          lg[k] = expf(lg[k] - mx);
          sum += lg[k];
        }
        for (int off = 32; off > 0; off >>= 1) sum += __shfl_xor(sum, off, 64);
        const float inv = 1.f / sum;
#pragma unroll
        for (int k = 0; k < 8; ++k) s_w[u][lane + 64 * k] = lg[k] * inv;
      }
      __syncthreads();  // D

      // ---- stream: wave owns 64 rows; e/a pinned in regs; 4-row chunks ----
      {
        const int d4 = lane;
        float4 e0 = *(const float4*)&s_e[ub + 0][d4 * 4], a0 = *(const float4*)&s_a[ub + 0][d4 * 4];
        float4 e1 = *(const float4*)&s_e[ub + 1][d4 * 4], a1 = *(const float4*)&s_a[ub + 1][d4 * 4];
        float4 e2 = *(const float4*)&s_e[ub + 2][d4 * 4], a2 = *(const float4*)&s_a[ub + 2][d4 * 4];
        float4 e3 = *(const float4*)&s_e[ub + 3][d4 * 4], a3 = *(const float4*)&s_a[ub + 3][d4 * 4];
        float4 e4 = *(const float4*)&s_e[ub + 4][d4 * 4], a4 = *(const float4*)&s_a[ub + 4][d4 * 4];
        float4 e5 = *(const float4*)&s_e[ub + 5][d4 * 4], a5 = *(const float4*)&s_a[ub + 5][d4 * 4];
        float4 e6 = *(const float4*)&s_e[ub + 6][d4 * 4], a6 = *(const float4*)&s_a[ub + 6][d4 * 4];
        float4 e7 = *(const float4*)&s_e[ub + 7][d4 * 4], a7 = *(const float4*)&s_a[ub + 7][d4 * 4];
        PIN8(e0, a0); PIN8(e1, a1); PIN8(e2, a2); PIN8(e3, a3);
        PIN8(e4, a4); PIN8(e5, a5); PIN8(e6, a6); PIN8(e7, a7);
        float4 racc[U_];
#pragma unroll
        for (int u = 0; u < U_; ++u) racc[u] = make_float4(0.f, 0.f, 0.f, 0.f);
        const int n0 = wid * 64;
        half4 cA = stb[(n0 + 0) * 64 + d4];
        half4 cB = stb[(n0 + 1) * 64 + d4];
        half4 cC = stb[(n0 + 2) * 64 + d4];
        half4 cD = stb[(n0 + 3) * 64 + d4];
        for (int c = 0; c < 64; c += 4) {
          half4 nA, nB, nC, nD;
          const bool more = (c + 4) < 64;
          if (more) {
            nA = stb[(n0 + c + 4) * 64 + d4];
            nB = stb[(n0 + c + 5) * 64 + d4];
            nC = stb[(n0 + c + 6) * 64 + d4];
            nD = stb[(n0 + c + 7) * 64 + d4];
          }
          float4 mA = h2f(cA), mB = h2f(cB), mC = h2f(cC), mD = h2f(cD);
#pragma unroll
          for (int u = 0; u < U_; ++u) {
            const float4 eu = (u == 0) ? e0 : (u == 1) ? e1 : (u == 2) ? e2 : (u == 3) ? e3
                             : (u == 4) ? e4 : (u == 5) ? e5 : (u == 6) ? e6 : e7;
            const float4 au = (u == 0) ? a0 : (u == 1) ? a1 : (u == 2) ? a2 : (u == 3) ? a3
                             : (u == 4) ? a4 : (u == 5) ? a5 : (u == 6) ? a6 : a7;
            const float2 wAB = *(const float2*)&s_w[u][n0 + c];
            const float2 wCD = *(const float2*)&s_w[u][n0 + c + 2];
            const float w0 = wAB.x, w1 = wAB.y, w2 = wCD.x, w3 = wCD.y;
            racc[u].x = fmaf(w0, mA.x, racc[u].x); racc[u].y = fmaf(w0, mA.y, racc[u].y);
            racc[u].z = fmaf(w0, mA.z, racc[u].z); racc[u].w = fmaf(w0, mA.w, racc[u].w);
            mA.x = fmaf(-w0, fmaf(eu.x, mA.x, -au.x), mA.x);
            mA.y = fmaf(-w0, fmaf(eu.y, mA.y, -au.y), mA.y);
            mA.z = fmaf(-w0, fmaf(eu.z, mA.z, -au.z), mA.z);
            mA.w = fmaf(-w0, fmaf(eu.w, mA.w, -au.w), mA.w);
            racc[u].x = fmaf(w1, mB.x, racc[u].x); racc[u].y = fmaf(w1, mB.y, racc[u].y);
            racc[u].z = fmaf(w1, mB.z, racc[u].z); racc[u].w = fmaf(w1, mB.w, racc[u].w);
            mB.x = fmaf(-w1, fmaf(eu.x, mB.x, -au.x), mB.x);
            mB.y = fmaf(-w1, fmaf(eu.y, mB.y, -au.y), mB.y);
            mB.z = fmaf(-w1, fmaf(eu.z, mB.z, -au.z), mB.z);
            mB.w = fmaf(-w1, fmaf(eu.w, mB.w, -au.w), mB.w);
            racc[u].x = fmaf(w2, mC.x, racc[u].x); racc[u].y = fmaf(w2, mC.y, racc[u].y);
            racc[u].z = fmaf(w2, mC.z, racc[u].z); racc[u].w = fmaf(w2, mC.w, racc[u].w);
            mC.x = fmaf(-w2, fmaf(eu.x, mC.x, -au.x), mC.x);
            mC.y = fmaf(-w2, fmaf(eu.y, mC.y, -au.y), mC.y);
            mC.z = fmaf(-w2, fmaf(eu.z, mC.z, -au.z), mC.z);
            mC.w = fmaf(-w2, fmaf(eu.w, mC.w, -au.w), mC.w);
            racc[u].x = fmaf(w3, mD.x, racc[u].x); racc[u].y = fmaf(w3, mD.y, racc[u].y);
            racc[u].z = fmaf(w3, mD.z, racc[u].z); racc[u].w = fmaf(w3, mD.w, racc[u].w);
            mD.x = fmaf(-w3, fmaf(eu.x, mD.x, -au.x), mD.x);
            mD.y = fmaf(-w3, fmaf(eu.y, mD.y, -au.y), mD.y);
            mD.z = fmaf(-w3, fmaf(eu.z, mD.z, -au.z), mD.z);
            mD.w = fmaf(-w3, fmaf(eu.w, mD.w, -au.w), mD.w);
          }
          stb[(n0 + c + 0) * 64 + d4] = f2h(mA);
          stb[(n0 + c + 1) * 64 + d4] = f2h(mB);
          stb[(n0 + c + 2) * 64 + d4] = f2h(mC);
          stb[(n0 + c + 3) * 64 + d4] = f2h(mD);
          if (more) { cA = nA; cB = nB; cC = nC; cD = nD; }
        }
#pragma unroll
        for (int u = 0; u < U_; ++u) {
          atomicAdd(&s_r[u][d4 * 4 + 0], racc[u].x);
          atomicAdd(&s_r[u][d4 * 4 + 1], racc[u].y);
          atomicAdd(&s_r[u][d4 * 4 + 2], racc[u].z);
          atomicAdd(&s_r[u][d4 * 4 + 3], racc[u].w);
        }
      }
      __syncthreads();  // E

      // ---- MLP layer 1 (8 waves, u=wid) ----
      {
        const int u = wid;
        float acc = b1[lane];
        const float4* w1r = (const float4*)(W1 + lane * (DV_ + DK_));
#pragma unroll
        for (int kk = 0; kk < DV_ / 4; ++kk)
          acc += dot4(w1r[kk], *(const float4*)&s_r[u][kk * 4]);
#pragma unroll
        for (int kk = 0; kk < DK_ / 4; ++kk)
          acc += dot4(w1r[DV_ / 4 + kk], *(const float4*)&s_q[u][kk * 4]);
        s_h1[u][lane] = fmaxf(acc, 0.f);
      }
      __syncthreads();  // F

      // ---- MLP layer 2 + head ----
      {
        const int u = wid;
        float acc = b2[lane];
        const float4* w2r = (const float4*)(W2 + lane * S_);
#pragma unroll
        for (int kk = 0; kk < S_ / 4; ++kk)
          acc += dot4(w2r[kk], *(const float4*)&s_h1[u][kk * 4]);
        float pp = fmaxf(acc, 0.f) * W3[lane];
        for (int off = 32; off > 0; off >>= 1) pp += __shfl_xor(pp, off, 64);
        if (lane == 0)
          out[(size_t)b * T_ + t0 + u] = 1.f / (1.f + expf(-(pp + b3[0])));
      }
    }  // pass
  }    // super-pass
}

extern "C" void kernel_launch(void* const* d_in, const int* in_sizes, int n_in,
                              void* d_out, int out_size, void* d_ws, size_t ws_size,
                              hipStream_t stream) {
  const int* concepts = (const int*)d_in[0];
  const int* interactions = (const int*)d_in[1];
  const float* Kmem = (const float*)d_in[2];
  const float* Vmem = (const float*)d_in[3];
  const float* cemb = (const float*)d_in[4];
  const float* iemb = (const float*)d_in[5];
  const float* We = (const float*)d_in[6];
  const float* be = (const float*)d_in[7];
  const float* Wa = (const float*)d_in[8];
  const float* ba = (const float*)d_in[9];
  const float* W1 = (const float*)d_in[10];
  const float* b1 = (const float*)d_in[11];
  const float* W2 = (const float*)d_in[12];
  const float* b2 = (const float*)d_in[13];
  const float* W3 = (const float*)d_in[14];
  const float* b3 = (const float*)d_in[15];
  float* out = (float*)d_out;
  h16* state = (h16*)d_ws;  // B*N*DV fp16 = 64 MiB

  dkvmn_fused<<<dim3(B_), dim3(NTB), 0, stream>>>(
      concepts, interactions, Kmem, Vmem, cemb, iemb, We, be, Wa, ba,
      W1, b1, W2, b2, W3, b3, out, state);
}